// Round 1
// baseline (1009.469 us; speedup 1.0000x reference)
//
#include <hip/hip_runtime.h>

typedef __attribute__((ext_vector_type(8))) short bf16x8;
typedef __attribute__((ext_vector_type(4))) float f32x4;
typedef unsigned short u16;
typedef unsigned int   u32;

#define NTOK  196
#define NH    8
#define KD    32
#define DVDIM 128
#define CDIM  512
#define DH    1024
#define SCALE_F 0.17677669529663687f  // 32^-0.5

__device__ __forceinline__ u16 f2bf(float f) {
  u32 u = __builtin_bit_cast(u32, f);
  u32 r = u + 0x7FFFu + ((u >> 16) & 1u);   // RNE
  return (u16)(r >> 16);
}
__device__ __forceinline__ u32 pack2(float a, float b) {
  return (u32)f2bf(a) | ((u32)f2bf(b) << 16);
}
__device__ __forceinline__ uint4 cvt8(float4 a, float4 b) {
  uint4 u;
  u.x = pack2(a.x, a.y); u.y = pack2(a.z, a.w);
  u.z = pack2(b.x, b.y); u.w = pack2(b.z, b.w);
  return u;
}

// ---------------------------------------------------------------------------
// Generic 128x128 MFMA GEMM, C[m][n] = sum_k A[m][k] * W[n][k] + bias[n]
// A: fp32 (inline-converted) or bf16.  W: fp32 [N][K] (inline-converted).
// EPI 0: scatter bf16 into qkv (B,H,N,192) layout.  EPI 1: fp32 row-major out.
// ---------------------------------------------------------------------------
template<int K, bool ABF16, int EPI>
__global__ __launch_bounds__(256)
void gemm_k(const void* __restrict__ Aptr, const float* __restrict__ Bw,
            const float* __restrict__ bias, void* __restrict__ outp)
{
  __shared__ __align__(16) u16 As[128][40];  // [m][k], +8 pad
  __shared__ __align__(16) u16 Bs[128][40];  // [n][k], +8 pad
  const int tid  = threadIdx.x;
  const int bm   = blockIdx.x, bn = blockIdx.y;
  const int lane = tid & 63,  wv = tid >> 6;
  const int wm   = (wv >> 1) * 64, wn = (wv & 1) * 64;
  const int c16  = lane & 15, quad = lane >> 4;
  const int row  = tid >> 1,  ch   = (tid & 1) * 16;
  f32x4 acc[4][4] = {};

  for (int k0 = 0; k0 < K; k0 += 32) {
    if (ABF16) {
      const u16* Ab = (const u16*)Aptr + (size_t)(bm * 128 + row) * K + k0 + ch;
      uint4 u0 = ((const uint4*)Ab)[0], u1 = ((const uint4*)Ab)[1];
      *(uint4*)&As[row][ch]     = u0;
      *(uint4*)&As[row][ch + 8] = u1;
    } else {
      const float4* pa = (const float4*)((const float*)Aptr + (size_t)(bm * 128 + row) * K + k0 + ch);
      float4 a0 = pa[0], a1 = pa[1], a2 = pa[2], a3 = pa[3];
      *(uint4*)&As[row][ch]     = cvt8(a0, a1);
      *(uint4*)&As[row][ch + 8] = cvt8(a2, a3);
    }
    {
      const float4* pb = (const float4*)(Bw + (size_t)(bn * 128 + row) * K + k0 + ch);
      float4 b0 = pb[0], b1 = pb[1], b2 = pb[2], b3 = pb[3];
      *(uint4*)&Bs[row][ch]     = cvt8(b0, b1);
      *(uint4*)&Bs[row][ch + 8] = cvt8(b2, b3);
    }
    __syncthreads();
    bf16x8 af[4], bf[4];
    #pragma unroll
    for (int mi = 0; mi < 4; ++mi)
      af[mi] = *(const bf16x8*)&As[wm + mi * 16 + c16][quad * 8];
    #pragma unroll
    for (int ni = 0; ni < 4; ++ni)
      bf[ni] = *(const bf16x8*)&Bs[wn + ni * 16 + c16][quad * 8];
    #pragma unroll
    for (int mi = 0; mi < 4; ++mi)
      #pragma unroll
      for (int ni = 0; ni < 4; ++ni)
        acc[mi][ni] = __builtin_amdgcn_mfma_f32_16x16x32_bf16(af[mi], bf[ni], acc[mi][ni], 0, 0, 0);
    __syncthreads();
  }

  #pragma unroll
  for (int mi = 0; mi < 4; ++mi) {
    #pragma unroll
    for (int ni = 0; ni < 4; ++ni) {
      const int gn = bn * 128 + wn + ni * 16 + c16;
      const float bv = bias[gn];
      #pragma unroll
      for (int r = 0; r < 4; ++r) {
        const int gm = bm * 128 + wm + mi * 16 + quad * 4 + r;
        const float v = acc[mi][ni][r] + bv;
        if (EPI == 0) {
          const int bb = gm / NTOK, t = gm - bb * NTOK;
          const int hh = gn / 192,  d = gn - hh * 192;
          ((u16*)outp)[(((size_t)bb * NH + hh) * NTOK + t) * 192 + d] = f2bf(v);
        } else {
          ((float*)outp)[(size_t)gm * CDIM + gn] = v;
        }
      }
    }
  }
}

// ---------------------------------------------------------------------------
// Flash-style attention. grid (B*H, 2); block = 256 thr = 4 waves.
// blockIdx.y selects query row-tile range (7 tiles / 6 tiles of 16 rows).
// Keys streamed in 4 chunks of 64; online softmax state in registers.
// qkvb layout: (B,H,196,192) bf16, d: [0,32)=q [32,64)=k [64,192)=v.
// ---------------------------------------------------------------------------
__global__ __launch_bounds__(256)
void attn_k(const u16* __restrict__ qkvb, const float* __restrict__ ab,
            const int* __restrict__ bidx, u16* __restrict__ Ob)
{
  __shared__ __align__(16) u16 k_s[64][40];        // [key][kd]
  __shared__ __align__(16) u16 vt_s[128][72];      // [dv][key] (transposed)
  __shared__ __align__(16) u16 p_s[4][16][72];     // per-wave P tile [m][key]
  __shared__ float bias_s[196];

  const int bh = blockIdx.x;
  const int b  = bh >> 3, h = bh & 7;
  const int tstart = blockIdx.y * 7;
  const int tcount = (blockIdx.y == 0) ? 7 : 6;    // 13 tiles total
  const u16* base = qkvb + (size_t)bh * (NTOK * 192);
  const int tid  = threadIdx.x;
  const int lane = tid & 63, w = tid >> 6;
  const int c16  = lane & 15, quad = lane >> 4;

  if (tid < 196) bias_s[tid] = ab[h * 196 + tid];

  // Q fragments straight from global (16B per lane, contiguous per row)
  bf16x8 aq[2];
  #pragma unroll
  for (int s = 0; s < 2; ++s) {
    const int ti  = tstart + w + s * 4;
    const int tok = min(ti * 16 + c16, NTOK - 1);
    aq[s] = *(const bf16x8*)(base + (size_t)tok * 192 + quad * 8);
  }

  float mx[2][4], l[2][4];
  f32x4 oacc[2][8] = {};
  #pragma unroll
  for (int s = 0; s < 2; ++s)
    #pragma unroll
    for (int r = 0; r < 4; ++r) { mx[s][r] = -1e30f; l[s][r] = 0.f; }

  const f32x4 zf = {0.f, 0.f, 0.f, 0.f};

  for (int kc = 0; kc < 4; ++kc) {
    // stage K chunk (64 keys x 32)
    {
      const int krow = tid >> 2, part = tid & 3;
      const int key  = min(kc * 64 + krow, NTOK - 1);
      *(uint4*)&k_s[krow][part * 8] =
        *(const uint4*)(base + (size_t)key * 192 + KD + part * 8);
    }
    // stage V chunk transposed (64 keys x 128 dv)
    #pragma unroll
    for (int ii = 0; ii < 4; ++ii) {
      const int i = tid + ii * 256;
      const int t = i >> 4, dvb = (i & 15) * 8;
      const int key = min(kc * 64 + t, NTOK - 1);
      union { uint4 u; u16 s[8]; } vv;
      vv.u = *(const uint4*)(base + (size_t)key * 192 + 64 + dvb);
      #pragma unroll
      for (int j = 0; j < 8; ++j) vt_s[dvb + j][t] = vv.s[j];
    }
    __syncthreads();

    #pragma unroll
    for (int s = 0; s < 2; ++s) {
      const int ti = w + s * 4;
      if (ti < tcount) {
        const int m0 = (tstart + ti) * 16;
        f32x4 sc[4];
        #pragma unroll
        for (int nt = 0; nt < 4; ++nt) {
          bf16x8 bk = *(const bf16x8*)&k_s[nt * 16 + c16][quad * 8];
          sc[nt] = __builtin_amdgcn_mfma_f32_16x16x32_bf16(aq[s], bk, zf, 0, 0, 0);
        }
        #pragma unroll
        for (int r = 0; r < 4; ++r) {
          const int m = m0 + quad * 4 + r;
          float vals[4];
          float cmx = -1e30f;
          #pragma unroll
          for (int nt = 0; nt < 4; ++nt) {
            const int j = kc * 64 + nt * 16 + c16;
            float v = -1e30f;
            if (m < NTOK && j < NTOK)
              v = sc[nt][r] * SCALE_F + bias_s[bidx[m * NTOK + j]];
            vals[nt] = v;
            cmx = fmaxf(cmx, v);
          }
          #pragma unroll
          for (int o = 1; o < 16; o <<= 1) cmx = fmaxf(cmx, __shfl_xor(cmx, o));
          const float nmx   = fmaxf(mx[s][r], cmx);
          const float alpha = __expf(mx[s][r] - nmx);
          mx[s][r] = nmx;
          float csum = 0.f;
          #pragma unroll
          for (int nt = 0; nt < 4; ++nt) {
            const float p = __expf(vals[nt] - nmx);
            vals[nt] = p;
            csum += p;
          }
          #pragma unroll
          for (int o = 1; o < 16; o <<= 1) csum += __shfl_xor(csum, o);
          l[s][r] = l[s][r] * alpha + csum;
          #pragma unroll
          for (int nt = 0; nt < 8; ++nt) oacc[s][nt][r] *= alpha;
          #pragma unroll
          for (int nt = 0; nt < 4; ++nt)
            p_s[w][quad * 4 + r][nt * 16 + c16] = f2bf(vals[nt]);
        }
        // PV: O += P (16x64) * V (64x128)
        #pragma unroll
        for (int ks = 0; ks < 2; ++ks) {
          bf16x8 ap = *(const bf16x8*)&p_s[w][c16][ks * 32 + quad * 8];
          #pragma unroll
          for (int nt = 0; nt < 8; ++nt) {
            bf16x8 bv = *(const bf16x8*)&vt_s[nt * 16 + c16][ks * 32 + quad * 8];
            oacc[s][nt] = __builtin_amdgcn_mfma_f32_16x16x32_bf16(ap, bv, oacc[s][nt], 0, 0, 0);
          }
        }
      }
    }
    __syncthreads();
  }

  // epilogue: normalize and store O as bf16 (B, N, 1024)
  #pragma unroll
  for (int s = 0; s < 2; ++s) {
    const int ti = w + s * 4;
    if (ti >= tcount) continue;
    const int m0 = (tstart + ti) * 16;
    #pragma unroll
    for (int r = 0; r < 4; ++r) {
      const int m = m0 + quad * 4 + r;
      if (m >= NTOK) continue;
      const float rl = 1.0f / fmaxf(l[s][r], 1e-30f);
      #pragma unroll
      for (int nt = 0; nt < 8; ++nt)
        Ob[((size_t)b * NTOK + m) * DH + h * DVDIM + nt * 16 + c16] =
          f2bf(oacc[s][nt][r] * rl);
    }
  }
}

// ---------------------------------------------------------------------------
extern "C" void kernel_launch(void* const* d_in, const int* in_sizes, int n_in,
                              void* d_out, int out_size, void* d_ws, size_t ws_size,
                              hipStream_t stream) {
  const float* x      = (const float*)d_in[0];   // (256,196,512)
  const float* qkv_w  = (const float*)d_in[1];   // (1536,512)
  const float* qkv_b  = (const float*)d_in[2];   // (1536,)
  const float* proj_w = (const float*)d_in[3];   // (512,1024)
  const float* proj_b = (const float*)d_in[4];   // (512,)
  const float* ab     = (const float*)d_in[5];   // (8,196)
  const int*   bidx   = (const int*)d_in[6];     // (196,196) int32
  float* out = (float*)d_out;                    // (256,196,512) fp32

  // workspace: qkvb bf16 (B,H,196,192) = 154,140,672 B ; Ob bf16 (B,196,1024)
  u16* qkvb = (u16*)d_ws;
  u16* Ob   = (u16*)((char*)d_ws + (size_t)154140672);

  // 1) QKV GEMM: M=50176 (392 tiles), N=1536 (12 tiles), K=512
  gemm_k<512, false, 0><<<dim3(392, 12), 256, 0, stream>>>(
      (const void*)x, qkv_w, qkv_b, (void*)qkvb);

  // 2) attention: (B*H) x 2 row-tile halves
  attn_k<<<dim3(2048, 2), 256, 0, stream>>>(qkvb, ab, bidx, Ob);

  // 3) proj GEMM: M=50176, N=512 (4 tiles), K=1024
  gemm_k<1024, true, 1><<<dim3(392, 4), 256, 0, stream>>>(
      (const void*)Ob, proj_w, proj_b, (void*)out);
}

// Round 3
// 539.156 us; speedup vs baseline: 1.8723x; 1.8723x over previous
//
#include <hip/hip_runtime.h>

typedef __attribute__((ext_vector_type(8))) short bf16x8;
typedef __attribute__((ext_vector_type(4))) float f32x4;
typedef unsigned short u16;
typedef unsigned int   u32;

#define NTOK  196
#define NH    8
#define DVDIM 128
#define CDIM  512
#define DH    1024
// 32^-0.5 * log2(e)  (log2e folded into scale; bias table pre-scaled too)
#define SCALE2 0.25505654708103197f
#define NEG_BIG -1.0e30f
#define LOG2E 1.4426950408889634f
#define VSTRIDE 200   // vT row stride (elements); keeps all b128 loads 16B-aligned

__device__ __forceinline__ u16 f2bf(float f) {
  u32 u = __builtin_bit_cast(u32, f);
  u32 r = u + 0x7FFFu + ((u >> 16) & 1u);   // RNE
  return (u16)(r >> 16);
}

// 16B async global->LDS; lds_wave_base must be wave-uniform (HW adds lane*16)
__device__ __forceinline__ void stage16(const void* g, char* lds_wave_base, int lane) {
#if __has_builtin(__builtin_amdgcn_global_load_lds)
  __builtin_amdgcn_global_load_lds(
      (const __attribute__((address_space(1))) unsigned int*)g,
      (__attribute__((address_space(3))) unsigned int*)lds_wave_base, 16, 0, 0);
#else
  *(uint4*)(lds_wave_base + lane * 16) = *(const uint4*)g;
#endif
}

// ---------------------------------------------------------------------------
// fp32 -> bf16 bulk convert (n8 = count/8, exact)
// ---------------------------------------------------------------------------
__global__ __launch_bounds__(256)
void cvt_k(const float* __restrict__ s, u16* __restrict__ d, int n8) {
  int i = blockIdx.x * 256 + threadIdx.x;
  if (i < n8) {
    const float4* sp = (const float4*)s + (size_t)i * 2;
    float4 a = sp[0], b = sp[1];
    uint4 o;
    o.x = (u32)f2bf(a.x) | ((u32)f2bf(a.y) << 16);
    o.y = (u32)f2bf(a.z) | ((u32)f2bf(a.w) << 16);
    o.z = (u32)f2bf(b.x) | ((u32)f2bf(b.y) << 16);
    o.w = (u32)f2bf(b.z) | ((u32)f2bf(b.w) << 16);
    ((uint4*)d)[i] = o;
  }
}

// ---------------------------------------------------------------------------
// biasT[h][key 256][query 224] = ab[h][bidx[query][key]] * LOG2E, pads -1e30
// ---------------------------------------------------------------------------
__global__ __launch_bounds__(224)
void biasT_k(const float* __restrict__ ab, const int* __restrict__ bidx,
             float* __restrict__ bT) {
  const int m = threadIdx.x, j = blockIdx.x, h = blockIdx.y;
  float v = NEG_BIG;
  if (j < NTOK && m < NTOK) v = ab[h * NTOK + bidx[m * NTOK + j]] * LOG2E;
  bT[((size_t)h * 256 + j) * 224 + m] = v;
}

// ---------------------------------------------------------------------------
// 128x128 MFMA GEMM (bf16 A,W; fp32 acc), global_load_lds staging.
// D[m][n] = sum_k A[m][k] W[n][k] + bias[n].
// 1-D grid, XCD swizzle: bid&7 -> xcd; blocks sharing an A panel adjacent.
// EPI 0: scatter q/k/vT bf16 workspace.  EPI 1: fp32 row-major + bias.
// ---------------------------------------------------------------------------
template<int K, int NB, int EPI>
__global__ __launch_bounds__(256)
void gemm_k(const u16* __restrict__ A, const u16* __restrict__ W,
            const float* __restrict__ bias,
            u16* __restrict__ q, u16* __restrict__ kk, u16* __restrict__ vT,
            float* __restrict__ out)
{
  __shared__ __align__(16) u16 As[128 * 32];
  __shared__ __align__(16) u16 Bs[128 * 32];
  const int tid  = threadIdx.x;
  const int bid  = blockIdx.x;
  const int xcd  = bid & 7, t = bid >> 3;
  const int bn   = t % NB, bm = xcd * 49 + t / NB;   // 392 = 8*49
  const int lane = tid & 63, w = tid >> 6;
  const int c16  = lane & 15, quad = lane >> 4;
  const int wm   = (w >> 1) * 64, wn = (w & 1) * 64;
  f32x4 acc[4][4] = {};

  const u16* Ab = A + (size_t)bm * 128 * K;
  const u16* Wb = W + (size_t)bn * 128 * K;
  char* ldsA = (char*)As + w * 1024;
  char* ldsB = (char*)Bs + w * 1024;

  for (int k0 = 0; k0 < K; k0 += 32) {
    #pragma unroll
    for (int p = 0; p < 2; ++p) {
      const int i = p * 256 + tid;
      const int m = i >> 2, kp = (i & 3) * 8;
      stage16(Ab + (size_t)m * K + k0 + kp, ldsA + p * 4096, lane);
      stage16(Wb + (size_t)m * K + k0 + kp, ldsB + p * 4096, lane);
    }
    __syncthreads();
    bf16x8 af[4], bfr[4];
    #pragma unroll
    for (int mi = 0; mi < 4; ++mi)
      af[mi] = *(const bf16x8*)&As[(wm + mi * 16 + c16) * 32 + quad * 8];
    #pragma unroll
    for (int ni = 0; ni < 4; ++ni)
      bfr[ni] = *(const bf16x8*)&Bs[(wn + ni * 16 + c16) * 32 + quad * 8];
    #pragma unroll
    for (int mi = 0; mi < 4; ++mi)
      #pragma unroll
      for (int ni = 0; ni < 4; ++ni)
        acc[mi][ni] = __builtin_amdgcn_mfma_f32_16x16x32_bf16(af[mi], bfr[ni], acc[mi][ni], 0, 0, 0);
    __syncthreads();
  }

  if (EPI == 0) {
    #pragma unroll
    for (int ni = 0; ni < 4; ++ni) {
      const int gn = bn * 128 + wn + ni * 16 + c16;
      const int h = gn / 192, d = gn - h * 192;
      const float bv = bias[gn];
      #pragma unroll
      for (int mi = 0; mi < 4; ++mi) {
        const int gm0 = bm * 128 + wm + mi * 16 + quad * 4;
        const int bb = gm0 / 196, tok0 = gm0 - bb * 196;  // tok0..tok0+3 same batch
        const size_t bhh = (size_t)bb * 8 + h;
        const float v0 = acc[mi][ni][0] + bv, v1 = acc[mi][ni][1] + bv;
        const float v2 = acc[mi][ni][2] + bv, v3 = acc[mi][ni][3] + bv;
        if (d < 64) {
          u16* dst = (d < 32) ? (q  + (bhh * 196 + tok0) * 32 + d)
                              : (kk + (bhh * 196 + tok0) * 32 + (d - 32));
          dst[0] = f2bf(v0); dst[32] = f2bf(v1); dst[64] = f2bf(v2); dst[96] = f2bf(v3);
        } else {
          ushort4 pk = { f2bf(v0), f2bf(v1), f2bf(v2), f2bf(v3) };
          *(ushort4*)&vT[(bhh * 128 + (d - 64)) * VSTRIDE + tok0] = pk;
        }
      }
    }
  } else {
    #pragma unroll
    for (int ni = 0; ni < 4; ++ni) {
      const int gn = bn * 128 + wn + ni * 16 + c16;
      const float bv = bias[gn];
      #pragma unroll
      for (int mi = 0; mi < 4; ++mi) {
        const int gm0 = bm * 128 + wm + mi * 16 + quad * 4;
        #pragma unroll
        for (int r = 0; r < 4; ++r)
          out[(size_t)(gm0 + r) * CDIM + gn] = acc[mi][ni][r] + bv;
      }
    }
  }
}

// ---------------------------------------------------------------------------
// Attention, S^T formulation. grid (2048 bh, 2 halves) x 256 threads.
// S^T = K*Q^T -> softmax state per query COLUMN (c16); P exits in a layout
// writable with conflict-free b64 LDS stores; V^T pre-transposed in ws so
// staging is row-contiguous b128.
// ---------------------------------------------------------------------------
__global__ __launch_bounds__(256)
void attn_k(const u16* __restrict__ q, const u16* __restrict__ kk,
            const u16* __restrict__ vT, const float* __restrict__ bT,
            u16* __restrict__ Ob)
{
  __shared__ __align__(16) u16 k_s[64 * 40];        // [key][kd], stride 40
  __shared__ __align__(16) u16 vt_s[128 * 72];      // [dv][key], stride 72
  __shared__ __align__(16) u16 p_s[4 * 16 * 72];    // per-wave [query][key]

  const int bh = blockIdx.x;
  const int b = bh >> 3, h = bh & 7;
  const int tid = threadIdx.x;
  const int lane = tid & 63, w = tid >> 6;
  const int c16 = lane & 15, quad = lane >> 4;
  const u16* qb = q  + (size_t)bh * (NTOK * 32);
  const u16* kb = kk + (size_t)bh * (NTOK * 32);
  const u16* vb = vT + (size_t)bh * (DVDIM * VSTRIDE);
  const float* bTh = bT + (size_t)h * 256 * 224;
  const int tmax = blockIdx.y ? 6 : 7;              // 13 tiles total, skip dead #13

  int qt[2]; bool act[2]; bf16x8 qf[2];
  #pragma unroll
  for (int s = 0; s < 2; ++s) {
    const int ti = w + 4 * s;
    act[s] = (ti < tmax);
    qt[s] = blockIdx.y * 7 + ti;
    const int tok = min(qt[s] * 16 + c16, NTOK - 1);
    qf[s] = *(const bf16x8*)(qb + (size_t)tok * 32 + quad * 8);
  }
  float mx[2] = {NEG_BIG, NEG_BIG}, lsum[2] = {0.f, 0.f};
  f32x4 oacc[2][8] = {};
  const f32x4 zf = {0.f, 0.f, 0.f, 0.f};

  for (int kc = 0; kc < 4; ++kc) {
    {  // K chunk: 64 keys x 32 kd, b128 (dup key 195 for rows >195; P=0 there)
      const int key = min(kc * 64 + (tid >> 2), NTOK - 1);
      const int part = (tid & 3) * 8;
      *(uint4*)&k_s[(tid >> 2) * 40 + part] = *(const uint4*)(kb + (size_t)key * 32 + part);
    }
    #pragma unroll
    for (int it = 0; it < 4; ++it) {
      // V^T chunk: 128 dv x 64 keys, row-contiguous b128.
      // col clamp to 192: kc<3 exact (col<=184); kc=3 places keys 192..195
      // exactly; pad cols (keys>=196) read in-row pad bytes (finite) * P=0.
      const int idx = tid + it * 256;
      const int dv = idx >> 3, kp = (idx & 7) * 8;
      const int col = min(kc * 64 + kp, 192);
      *(uint4*)&vt_s[dv * 72 + kp] = *(const uint4*)(vb + (size_t)dv * VSTRIDE + col);
    }
    __syncthreads();

    #pragma unroll
    for (int s = 0; s < 2; ++s) {
      if (act[s]) {
        f32x4 sc[4];
        #pragma unroll
        for (int nt = 0; nt < 4; ++nt) {   // S^T[key][query] = K*Q^T
          bf16x8 kf = *(const bf16x8*)&k_s[(nt * 16 + c16) * 40 + quad * 8];
          sc[nt] = __builtin_amdgcn_mfma_f32_16x16x32_bf16(kf, qf[s], zf, 0, 0, 0);
        }
        const int qg = qt[s] * 16 + c16;
        float cmx = NEG_BIG;
        #pragma unroll
        for (int nt = 0; nt < 4; ++nt) {
          const float* bp = bTh + (size_t)(kc * 64 + nt * 16 + quad * 4) * 224 + qg;
          #pragma unroll
          for (int r = 0; r < 4; ++r) {
            const float x = sc[nt][r] * SCALE2 + bp[r * 224];
            sc[nt][r] = x;
            cmx = fmaxf(cmx, x);
          }
        }
        cmx = fmaxf(cmx, __shfl_xor(cmx, 16));
        cmx = fmaxf(cmx, __shfl_xor(cmx, 32));
        const float nmx = fmaxf(mx[s], cmx);
        const float alpha = exp2f(mx[s] - nmx);
        mx[s] = nmx;
        float csum = 0.f;
        #pragma unroll
        for (int nt = 0; nt < 4; ++nt) {
          const float p0 = exp2f(sc[nt][0] - nmx), p1 = exp2f(sc[nt][1] - nmx);
          const float p2 = exp2f(sc[nt][2] - nmx), p3 = exp2f(sc[nt][3] - nmx);
          csum += (p0 + p1) + (p2 + p3);
          ushort4 pk = { f2bf(p0), f2bf(p1), f2bf(p2), f2bf(p3) };
          *(ushort4*)&p_s[(w * 16 + c16) * 72 + nt * 16 + quad * 4] = pk;
        }
        csum += __shfl_xor(csum, 16);
        csum += __shfl_xor(csum, 32);
        lsum[s] = lsum[s] * alpha + csum;
        float a4[4];
        #pragma unroll
        for (int r = 0; r < 4; ++r) a4[r] = __shfl(alpha, quad * 4 + r);
        #pragma unroll
        for (int nt = 0; nt < 8; ++nt)
          #pragma unroll
          for (int r = 0; r < 4; ++r) oacc[s][nt][r] *= a4[r];
        #pragma unroll
        for (int ks = 0; ks < 2; ++ks) {   // O += P * V  (same-wave LDS: in order)
          bf16x8 ap = *(const bf16x8*)&p_s[(w * 16 + c16) * 72 + ks * 32 + quad * 8];
          #pragma unroll
          for (int nt = 0; nt < 8; ++nt) {
            bf16x8 bv = *(const bf16x8*)&vt_s[(nt * 16 + c16) * 72 + ks * 32 + quad * 8];
            oacc[s][nt] = __builtin_amdgcn_mfma_f32_16x16x32_bf16(ap, bv, oacc[s][nt], 0, 0, 0);
          }
        }
      }
    }
    __syncthreads();
  }

  #pragma unroll
  for (int s = 0; s < 2; ++s) {
    if (!act[s]) continue;
    float lr[4];
    #pragma unroll
    for (int r = 0; r < 4; ++r) lr[r] = __shfl(lsum[s], quad * 4 + r);
    #pragma unroll
    for (int r = 0; r < 4; ++r) {
      const int m = qt[s] * 16 + quad * 4 + r;
      if (m < NTOK) {
        const float inv = 1.0f / lr[r];
        #pragma unroll
        for (int nt = 0; nt < 8; ++nt)
          Ob[((size_t)b * NTOK + m) * DH + h * DVDIM + nt * 16 + c16] =
              f2bf(oacc[s][nt][r] * inv);
      }
    }
  }
}

// ---------------------------------------------------------------------------
extern "C" void kernel_launch(void* const* d_in, const int* in_sizes, int n_in,
                              void* d_out, int out_size, void* d_ws, size_t ws_size,
                              hipStream_t stream) {
  const float* x      = (const float*)d_in[0];   // (256,196,512)
  const float* qkv_w  = (const float*)d_in[1];   // (1536,512)
  const float* qkv_b  = (const float*)d_in[2];   // (1536,)
  const float* proj_w = (const float*)d_in[3];   // (512,1024)
  const float* proj_b = (const float*)d_in[4];   // (512,)
  const float* ab     = (const float*)d_in[5];   // (8,49)
  const int*   bidx   = (const int*)d_in[6];     // (196,196) int32
  float* out = (float*)d_out;                    // (256,196,512) fp32

  char* p = (char*)d_ws;
  u16*   qw  = (u16*)(p);                        // 25,690,112 B
  u16*   kw  = (u16*)(p + 25690112);             // 25,690,112 B
  u16*   vTw = (u16*)(p + 51380224);             // 104,857,600 B [bh][128][200]
  u16*   w1b = (u16*)(p + 156237824);            // 1,572,864 B
  u16*   w3b = (u16*)(p + 157810688);            // 1,048,576 B
  float* bT  = (float*)(p + 158859264);          // 1,835,008 B [8][256][224]
  u16*   xb  = (u16*)(p + 160694272);            // 51,380,224 B (dead after gemm1)
  u16*   Ob  = (u16*)(p + 160694272);            // 102,760,448 B (aliases xb; safe)

  // precompute: bf16 casts + bias table
  cvt_k<<<12544, 256, 0, stream>>>(x,      xb,  3211264);
  cvt_k<<<  384, 256, 0, stream>>>(qkv_w,  w1b,   98304);
  cvt_k<<<  256, 256, 0, stream>>>(proj_w, w3b,   65536);
  biasT_k<<<dim3(256, 8), 224, 0, stream>>>(ab, bidx, bT);

  // QKV GEMM: M=50176(392), N=1536(12), K=512 ; scatter q/k/vT
  gemm_k<512, 12, 0><<<4704, 256, 0, stream>>>(xb, w1b, qkv_b, qw, kw, vTw, nullptr);

  // attention
  attn_k<<<dim3(2048, 2), 256, 0, stream>>>(qw, kw, vTw, bT, Ob);

  // proj GEMM: M=50176, N=512(4), K=1024 ; fp32 out + bias
  gemm_k<1024, 4, 1><<<1568, 256, 0, stream>>>(Ob, w3b, proj_b, nullptr, nullptr, nullptr, out);
}